// Round 1
// baseline (1609.927 us; speedup 1.0000x reference)
//
#include <hip/hip_runtime.h>
#include <hip/hip_fp16.h>
#include <math.h>

#define FIN 35
#define F1  64
#define BSZ 256          // nodes per dst bucket (fixed by facc = 256*64*4B = 64KB LDS)
#define BSH 8            // log2(BSZ)
#define NRG 8            // src ranges per dst bucket
#define RSH 14           // src range = 16384 nodes = 2MB of g1 (fits per-XCD 4MB L2)
#define PCH 8192         // edges per chunk in hist/place
#define KCAP 3584        // 512*7 >= NBK = ceil(n/256)*8 ; supports n <= 114688

// ---------- phase 1: per-chunk histogram of (dst-bucket, src-range) keys ----------
__global__ void k_hist(const int* __restrict__ src, const int* __restrict__ dst,
                       int* __restrict__ kcnt, int E, int NBK) {
    __shared__ int h[KCAP];
    int c = blockIdx.x, t = threadIdx.x;
    for (int i = t; i < KCAP; i += 256) h[i] = 0;
    __syncthreads();
    int e0 = c * PCH, e1 = min(e0 + PCH, E);
    bool al = ((((size_t)(dst + e0)) | ((size_t)(src + e0))) & 15) == 0;
    int nv = al ? ((e1 - e0) >> 2) : 0;
    const int4* d4 = (const int4*)(dst + e0);
    const int4* s4 = (const int4*)(src + e0);
    for (int i = t; i < nv; i += 256) {
        int4 d = d4[i]; int4 s = s4[i];
        atomicAdd(&h[((d.x >> BSH) << 3) | (s.x >> RSH)], 1);
        atomicAdd(&h[((d.y >> BSH) << 3) | (s.y >> RSH)], 1);
        atomicAdd(&h[((d.z >> BSH) << 3) | (s.z >> RSH)], 1);
        atomicAdd(&h[((d.w >> BSH) << 3) | (s.w >> RSH)], 1);
    }
    for (int e = e0 + (nv << 2) + t; e < e1; e += 256)
        atomicAdd(&h[((dst[e] >> BSH) << 3) | (src[e] >> RSH)], 1);
    __syncthreads();
    for (int k = t; k < NBK; k += 256) { int v = h[k]; if (v) atomicAdd(&kcnt[k], v); }
}

// ---------- phase 2: exclusive scan of key counts -> segment bases (NBK <= 4096) ----------
__global__ void k_scan_buck(const int* __restrict__ kcnt, int* __restrict__ boff,
                            int NBK, int E) {
    __shared__ int s[1024];
    int t = threadIdx.x;
    int base = t * 4;
    int a0 = (base     < NBK) ? kcnt[base]     : 0;
    int a1 = (base + 1 < NBK) ? kcnt[base + 1] : 0;
    int a2 = (base + 2 < NBK) ? kcnt[base + 2] : 0;
    int a3 = (base + 3 < NBK) ? kcnt[base + 3] : 0;
    int p1 = a0, p2 = p1 + a1, p3 = p2 + a2, tot = p3 + a3;
    s[t] = tot;
    __syncthreads();
    #pragma unroll
    for (int off = 1; off < 1024; off <<= 1) {
        int tv = (t >= off) ? s[t - off] : 0;
        __syncthreads();
        s[t] += tv;
        __syncthreads();
    }
    int tex = s[t] - tot;
    if (base     < NBK) boff[base]     = tex;
    if (base + 1 < NBK) boff[base + 1] = tex + p1;
    if (base + 2 < NBK) boff[base + 2] = tex + p2;
    if (base + 3 < NBK) boff[base + 3] = tex + p3;
    if (t == 0) boff[NBK] = E;
}

// ---------- phase 3: placement — LDS counting sort per chunk, atomic window claim,
// ---------- coalesced bucket-major output. rec = (src<<7 | dl<<24, ew) ----------
__global__ __launch_bounds__(512) void k_place(
        const int* __restrict__ src, const int* __restrict__ dst,
        const float* __restrict__ ew, const int* __restrict__ boff,
        int* __restrict__ gcur, int2* __restrict__ recs, int E, int NBK) {
    extern __shared__ char pmem[];
    int2* lrec   = (int2*)pmem;              // PCH records (64 KB)
    int*  addr32 = (int*)(lrec + PCH);       // PCH global addresses (32 KB)
    int*  s      = addr32 + PCH;             // KCAP counts -> exclusive prefix
    int*  cur    = s + KCAP;                 // KCAP chunk-local cursors
    int*  gwin   = cur + KCAP;               // KCAP global window bases
    __shared__ int ts[512];
    int c = blockIdx.x, t = threadIdx.x;
    for (int i = t; i < KCAP; i += 512) { s[i] = 0; cur[i] = 0; }
    __syncthreads();
    int e0 = c * PCH, e1 = min(e0 + PCH, E);
    bool al = ((((size_t)(dst + e0)) | ((size_t)(src + e0)) | ((size_t)(ew + e0))) & 15) == 0;
    int nv = al ? ((e1 - e0) >> 2) : 0;
    const int4*   s4 = (const int4*)(src + e0);
    const int4*   d4 = (const int4*)(dst + e0);
    const float4* w4 = (const float4*)(ew + e0);
    // pass A: count per key
    for (int i = t; i < nv; i += 512) {
        int4 d = d4[i]; int4 sv = s4[i];
        atomicAdd(&s[((d.x >> BSH) << 3) | (sv.x >> RSH)], 1);
        atomicAdd(&s[((d.y >> BSH) << 3) | (sv.y >> RSH)], 1);
        atomicAdd(&s[((d.z >> BSH) << 3) | (sv.z >> RSH)], 1);
        atomicAdd(&s[((d.w >> BSH) << 3) | (sv.w >> RSH)], 1);
    }
    for (int e = e0 + (nv << 2) + t; e < e1; e += 512)
        atomicAdd(&s[((dst[e] >> BSH) << 3) | (src[e] >> RSH)], 1);
    __syncthreads();
    // claim global windows (order within a segment is irrelevant: sums commute)
    for (int k = t; k < NBK; k += 512) {
        int lc = s[k];
        if (lc) gwin[k] = boff[k] + atomicAdd(&gcur[k], lc);
    }
    __syncthreads();
    // in-place exclusive scan of s over KCAP = 512*7 (7 elems/thread + HS over thread sums)
    int base = t * 7;
    int a0=s[base],a1=s[base+1],a2=s[base+2],a3=s[base+3],a4=s[base+4],a5=s[base+5],a6=s[base+6];
    int p1=a0,p2=p1+a1,p3=p2+a2,p4=p3+a3,p5=p4+a4,p6=p5+a5,tot=p6+a6;
    ts[t] = tot;
    __syncthreads();
    #pragma unroll
    for (int off = 1; off < 512; off <<= 1) {
        int tv = (t >= off) ? ts[t - off] : 0;
        __syncthreads();
        ts[t] += tv;
        __syncthreads();
    }
    int tex = ts[t] - tot;
    s[base]=tex; s[base+1]=tex+p1; s[base+2]=tex+p2; s[base+3]=tex+p3;
    s[base+4]=tex+p4; s[base+5]=tex+p5; s[base+6]=tex+p6;
    __syncthreads();
    // pass B: scatter into LDS (record + final global address)
    for (int i = t; i < nv; i += 512) {
        int4 sv = s4[i]; int4 d = d4[i]; float4 wv = w4[i];
        int k, r, sl;
        k=((d.x>>BSH)<<3)|(sv.x>>RSH); r=atomicAdd(&cur[k],1); sl=s[k]+r;
        lrec[sl]=make_int2((sv.x<<7)|((d.x&(BSZ-1))<<24), __float_as_int(wv.x)); addr32[sl]=gwin[k]+r;
        k=((d.y>>BSH)<<3)|(sv.y>>RSH); r=atomicAdd(&cur[k],1); sl=s[k]+r;
        lrec[sl]=make_int2((sv.y<<7)|((d.y&(BSZ-1))<<24), __float_as_int(wv.y)); addr32[sl]=gwin[k]+r;
        k=((d.z>>BSH)<<3)|(sv.z>>RSH); r=atomicAdd(&cur[k],1); sl=s[k]+r;
        lrec[sl]=make_int2((sv.z<<7)|((d.z&(BSZ-1))<<24), __float_as_int(wv.z)); addr32[sl]=gwin[k]+r;
        k=((d.w>>BSH)<<3)|(sv.w>>RSH); r=atomicAdd(&cur[k],1); sl=s[k]+r;
        lrec[sl]=make_int2((sv.w<<7)|((d.w&(BSZ-1))<<24), __float_as_int(wv.w)); addr32[sl]=gwin[k]+r;
    }
    for (int e = e0 + (nv << 2) + t; e < e1; e += 512) {
        int d = dst[e];
        int k = ((d >> BSH) << 3) | (src[e] >> RSH);
        int r = atomicAdd(&cur[k], 1); int sl = s[k] + r;
        lrec[sl] = make_int2((src[e] << 7) | ((d & (BSZ-1)) << 24), __float_as_int(ew[e]));
        addr32[sl] = gwin[k] + r;
    }
    __syncthreads();
    // pass C: linear LDS walk -> coalesced global stores
    int cnt = e1 - e0;
    for (int i = t; i < cnt; i += 512) recs[addr32[i]] = lrec[i];
}

// ---------- weighted in-degree -> dinv (replaces k_sort's pass 1) ----------
__global__ __launch_bounds__(256) void k_deg(
        const int* __restrict__ boff, const int2* __restrict__ recs,
        float* __restrict__ dinv, int n) {
    __shared__ float ds[BSZ];
    int t = threadIdx.x, b = blockIdx.x;
    ds[t] = 1.0f;                            // self-loop weight
    __syncthreads();
    int s0 = boff[b * NRG], s1 = boff[b * NRG + NRG];
    for (int i = s0 + t; i < s1; i += 256) {
        int2 rc = recs[i];
        atomicAdd(&ds[(unsigned)rc.x >> 24], __int_as_float(rc.y));
    }
    __syncthreads();
    int node = b * BSZ + t;
    if (node < n) dinv[node] = rsqrtf(ds[t]);
}

// ---------- layer 1 GEMM: g1 = fp16(dinv*x@W1), feature-INTERLEAVED rows ----------
// storage slot for feat f: pos = 2*(f&31) + (f>>5) -> a 4B lane-read delivers
// feats (ln, ln+32), making the LDS ds_add in k_agg1 bank-conflict-free.
__global__ void k_gemm1(const float* __restrict__ x, const float* __restrict__ W1,
                        const float* __restrict__ dinv, __half* __restrict__ g1, int n) {
    __shared__ float W1s[FIN * F1];
    __shared__ float xs[64 * FIN];
    int t = threadIdx.x;
    for (int i = t; i < (FIN * F1) / 4; i += 256) ((float4*)W1s)[i] = ((const float4*)W1)[i];
    int row0 = blockIdx.x * 64;
    int nrows = min(64, n - row0);
    const float* xbase = x + (size_t)row0 * FIN;
    int tot = nrows * FIN;
    int totv = tot >> 2;
    for (int i = t; i < totv; i += 256) ((float4*)xs)[i] = ((const float4*)xbase)[i];
    for (int i = (totv << 2) + t; i < tot; i += 256) xs[i] = xbase[i];
    __syncthreads();
    int wave = t >> 6, f = t & 63;
    int pos = ((f & 31) << 1) | (f >> 5);
    for (int rl = wave; rl < nrows; rl += 4) {
        float acc = 0.0f;
        #pragma unroll
        for (int k = 0; k < FIN; k++) acc += xs[rl * FIN + k] * W1s[k * F1 + f];
        int row = row0 + rl;
        g1[(size_t)row * F1 + pos] = __float2half(acc * dinv[row]);
    }
}

// ---------- fused layer-1 aggregate (LDS accumulate, src-range blocked)
// ---------- + self-loop + bias + ReLU + layer-2 GEMM (64->2) ----------
__global__ __launch_bounds__(512) void k_agg1(
        const int* __restrict__ boff, const int2* __restrict__ recs,
        const __half* __restrict__ g1, const float* __restrict__ dinv,
        const float* __restrict__ b1, const float* __restrict__ W2,
        float* __restrict__ g2, int n) {
    extern __shared__ float facc[];          // BSZ*F1 fp32 = 64 KB
    int t = threadIdx.x, b = blockIdx.x;
    for (int i = t; i < (BSZ * F1) >> 2; i += 512)
        ((float4*)facc)[i] = make_float4(0.f, 0.f, 0.f, 0.f);
    __syncthreads();
    int wv = t >> 6;                         // wave 0..7
    int hl = (t >> 5) & 1;                   // half-wave -> record selector
    int ln = t & 31;                         // lane within half-wave
    const char* g1b = (const char*)g1 + (ln << 2);
    const long long* rr = (const long long*)recs;
    #pragma unroll 1
    for (int r = 0; r < NRG; r++) {          // ranges in order: g1 window L2-resident
        int s0 = boff[b * NRG + r], s1 = boff[b * NRG + r + 1];
        for (int base = s0 + wv * 16; base < s1; base += 128) {
            if (base + 16 <= s1) {
                long long q[8];
                #pragma unroll
                for (int j = 0; j < 8; j++)
                    q[j] = __builtin_nontemporal_load(rr + base + 2 * j + hl);
                unsigned hv[8];
                #pragma unroll
                for (int j = 0; j < 8; j++)
                    hv[j] = *(const unsigned*)(g1b + (unsigned)(q[j] & 0xFFFFFF));
                #pragma unroll
                for (int j = 0; j < 8; j++) {
                    float w = __int_as_float((int)(q[j] >> 32));
                    float2 fv = __half22float2(*(const __half2*)&hv[j]);
                    int fi = ((((unsigned)(int)q[j]) >> 24) << 6) + ln;
                    atomicAdd(&facc[fi],      w * fv.x);   // feat ln
                    atomicAdd(&facc[fi + 32], w * fv.y);   // feat ln+32
                }
            } else {
                for (int j = 0; j < 8; j++) {
                    int idx = base + 2 * j + hl;
                    if (idx < s1) {
                        long long q = rr[idx];
                        unsigned hvv = *(const unsigned*)(g1b + (unsigned)(q & 0xFFFFFF));
                        float w = __int_as_float((int)(q >> 32));
                        float2 fv = __half22float2(*(const __half2*)&hvv);
                        int fi = ((((unsigned)(int)q) >> 24) << 6) + ln;
                        atomicAdd(&facc[fi],      w * fv.x);
                        atomicAdd(&facc[fi + 32], w * fv.y);
                    }
                }
            }
        }
    }
    __syncthreads();
    // epilogue: 8 waves x 32 nodes each
    int f = t & 63;
    float bf = b1[f];
    float2 w2v = ((const float2*)W2)[f];
    int pos = ((f & 31) << 1) | (f >> 5);
    for (int dl = wv; dl < BSZ; dl += 8) {
        int node = b * BSZ + dl;
        if (node >= n) break;
        float dv = dinv[node];
        float selfv = __half2float(g1[(size_t)node * F1 + pos]);
        float h = dv * (facc[(dl << 6) + f] + selfv) + bf;   // self-loop w=1
        h = h > 0.0f ? h : 0.0f;
        float z0 = h * w2v.x, z1 = h * w2v.y;
        #pragma unroll
        for (int off = 32; off > 0; off >>= 1) {
            z0 += __shfl_xor(z0, off, 64);
            z1 += __shfl_xor(z1, off, 64);
        }
        if (f == 0) {
            g2[(size_t)node * 2 + 0] = dv * z0;
            g2[(size_t)node * 2 + 1] = dv * z1;
        }
    }
}

// ---------- fused layer-2 aggregate (LDS accumulate) + bias + log_softmax ----------
__global__ __launch_bounds__(256) void k_agg2(
        const int* __restrict__ boff, const int2* __restrict__ recs,
        const float* __restrict__ g2, const float* __restrict__ dinv,
        const float* __restrict__ b2, float* __restrict__ out, int n) {
    __shared__ float a2[BSZ * 2];
    int t = threadIdx.x, b = blockIdx.x;
    a2[t] = 0.0f; a2[t + 256] = 0.0f;
    __syncthreads();
    int s0 = boff[b * NRG], s1 = boff[b * NRG + NRG];
    const char* g2b = (const char*)g2;
    int i = s0 + t;
    for (; i + 768 < s1; i += 1024) {        // 4 gathers in flight
        int2 r0 = recs[i], r1 = recs[i + 256], r2 = recs[i + 512], r3 = recs[i + 768];
        float2 v0 = *(const float2*)(g2b + (((unsigned)r0.x & 0xFFFFFF) >> 4));
        float2 v1 = *(const float2*)(g2b + (((unsigned)r1.x & 0xFFFFFF) >> 4));
        float2 v2 = *(const float2*)(g2b + (((unsigned)r2.x & 0xFFFFFF) >> 4));
        float2 v3 = *(const float2*)(g2b + (((unsigned)r3.x & 0xFFFFFF) >> 4));
        int d0 = (unsigned)r0.x >> 24, d1 = (unsigned)r1.x >> 24;
        int d2 = (unsigned)r2.x >> 24, d3 = (unsigned)r3.x >> 24;
        float w0 = __int_as_float(r0.y), w1 = __int_as_float(r1.y);
        float w2 = __int_as_float(r2.y), w3 = __int_as_float(r3.y);
        atomicAdd(&a2[d0*2], w0*v0.x); atomicAdd(&a2[d0*2+1], w0*v0.y);
        atomicAdd(&a2[d1*2], w1*v1.x); atomicAdd(&a2[d1*2+1], w1*v1.y);
        atomicAdd(&a2[d2*2], w2*v2.x); atomicAdd(&a2[d2*2+1], w2*v2.y);
        atomicAdd(&a2[d3*2], w3*v3.x); atomicAdd(&a2[d3*2+1], w3*v3.y);
    }
    for (; i < s1; i += 256) {
        int2 rc = recs[i];
        float2 gv = *(const float2*)(g2b + (((unsigned)rc.x & 0xFFFFFF) >> 4));
        float w = __int_as_float(rc.y);
        int dl = (unsigned)rc.x >> 24;
        atomicAdd(&a2[dl*2], w*gv.x); atomicAdd(&a2[dl*2+1], w*gv.y);
    }
    __syncthreads();
    int node = b * BSZ + t;
    if (node < n) {
        float dv = dinv[node];
        float2 sv = ((const float2*)g2)[node];     // self-loop
        float z0 = dv * (a2[t*2]     + sv.x) + b2[0];
        float z1 = dv * (a2[t*2 + 1] + sv.y) + b2[1];
        float m = fmaxf(z0, z1);
        float lse = m + logf(expf(z0 - m) + expf(z1 - m));
        ((float2*)out)[node] = make_float2(z0 - lse, z1 - lse);
    }
}

extern "C" void kernel_launch(void* const* d_in, const int* in_sizes, int n_in,
                              void* d_out, int out_size, void* d_ws, size_t ws_size,
                              hipStream_t stream) {
    const float* x  = (const float*)d_in[0];
    const int*   ei = (const int*)d_in[1];    // [2, E]: src row then dst row
    const float* ew = (const float*)d_in[2];
    const float* W1 = (const float*)d_in[3];
    const float* b1 = (const float*)d_in[4];
    const float* W2 = (const float*)d_in[5];
    const float* b2 = (const float*)d_in[6];
    float* out = (float*)d_out;

    int n = in_sizes[0] / FIN;
    int E = in_sizes[2];
    const int* src = ei;
    const int* dst = ei + E;
    int NB  = (n + BSZ - 1) / BSZ;            // 391 for n=100000
    int NBK = NB * NRG;                       // 3128 <= KCAP
    int NCHUNK = (E + PCH - 1) / PCH;         // 391 for E=3.2M

    // workspace carve-out, 16B-aligned
    char* ws = (char*)d_ws;
    size_t off = 0;
    auto alloc = [&](size_t bytes) -> void* {
        void* p = ws + off;
        off += (bytes + 15) & ~(size_t)15;
        return p;
    };
    int*    cnts = (int*)   alloc((size_t)2 * NBK * 4);  // kcnt | gcur
    int*    kcnt = cnts;
    int*    gcur = cnts + NBK;
    int*    boff = (int*)   alloc((size_t)(NBK + 1) * 4);
    float*  dinv = (float*) alloc((size_t)n * 4);
    int2*   recs = (int2*)  alloc((size_t)E * 8);        // 25.6 MB (key-grouped)
    __half* g1   = (__half*)alloc((size_t)n * F1 * 2);   // 12.8 MB
    float*  g2   = (float*) alloc((size_t)n * 2 * 4);

    size_t place_lds = (size_t)PCH * 8 + (size_t)PCH * 4 + 3 * (size_t)KCAP * 4; // 141.3 KB
    size_t agg1_lds  = (size_t)BSZ * F1 * 4;                                     // 64 KB

    hipMemsetAsync(cnts, 0, (size_t)2 * NBK * 4, stream);
    k_hist     <<<NCHUNK, 256, 0, stream>>>(src, dst, kcnt, E, NBK);
    k_scan_buck<<<1, 1024, 0, stream>>>(kcnt, boff, NBK, E);
    k_place    <<<NCHUNK, 512, place_lds, stream>>>(src, dst, ew, boff, gcur, recs, E, NBK);
    k_deg      <<<NB, 256, 0, stream>>>(boff, recs, dinv, n);
    k_gemm1    <<<(n + 63) / 64, 256, 0, stream>>>(x, W1, dinv, g1, n);
    k_agg1     <<<NB, 512, agg1_lds, stream>>>(boff, recs, g1, dinv, b1, W2, g2, n);
    k_agg2     <<<NB, 256, 0, stream>>>(boff, recs, g2, dinv, b2, out, n);
}

// Round 2
// 1607.027 us; speedup vs baseline: 1.0018x; 1.0018x over previous
//
#include <hip/hip_runtime.h>
#include <hip/hip_fp16.h>
#include <math.h>

#define FIN 35
#define F1  64
#define BSZ 256          // nodes per dst bucket (fixed by facc = 256*64*4B = 64KB LDS)
#define BSH 8            // log2(BSZ)
#define NRG 8            // src ranges per dst bucket
#define RSH 14           // src range = 16384 nodes = 2MB of g1 (fits per-XCD 4MB L2)
#define PCH 8192         // edges per chunk in hist/place
#define KCAP 3584        // 512*7 >= NBK = ceil(n/256)*8 ; supports n <= 114688

// ---------- phase 1: per-chunk histogram of (dst-bucket, src-range) keys ----------
__global__ void k_hist(const int* __restrict__ src, const int* __restrict__ dst,
                       int* __restrict__ kcnt, int E, int NBK) {
    __shared__ int h[KCAP];
    int c = blockIdx.x, t = threadIdx.x;
    for (int i = t; i < KCAP; i += 256) h[i] = 0;
    __syncthreads();
    int e0 = c * PCH, e1 = min(e0 + PCH, E);
    bool al = ((((size_t)(dst + e0)) | ((size_t)(src + e0))) & 15) == 0;
    int nv = al ? ((e1 - e0) >> 2) : 0;
    const int4* d4 = (const int4*)(dst + e0);
    const int4* s4 = (const int4*)(src + e0);
    for (int i = t; i < nv; i += 256) {
        int4 d = d4[i]; int4 s = s4[i];
        atomicAdd(&h[((d.x >> BSH) << 3) | (s.x >> RSH)], 1);
        atomicAdd(&h[((d.y >> BSH) << 3) | (s.y >> RSH)], 1);
        atomicAdd(&h[((d.z >> BSH) << 3) | (s.z >> RSH)], 1);
        atomicAdd(&h[((d.w >> BSH) << 3) | (s.w >> RSH)], 1);
    }
    for (int e = e0 + (nv << 2) + t; e < e1; e += 256)
        atomicAdd(&h[((dst[e] >> BSH) << 3) | (src[e] >> RSH)], 1);
    __syncthreads();
    for (int k = t; k < NBK; k += 256) { int v = h[k]; if (v) atomicAdd(&kcnt[k], v); }
}

// ---------- phase 2: exclusive scan of key counts -> segment bases (NBK <= 4096) ----------
__global__ void k_scan_buck(const int* __restrict__ kcnt, int* __restrict__ boff,
                            int NBK, int E) {
    __shared__ int s[1024];
    int t = threadIdx.x;
    int base = t * 4;
    int a0 = (base     < NBK) ? kcnt[base]     : 0;
    int a1 = (base + 1 < NBK) ? kcnt[base + 1] : 0;
    int a2 = (base + 2 < NBK) ? kcnt[base + 2] : 0;
    int a3 = (base + 3 < NBK) ? kcnt[base + 3] : 0;
    int p1 = a0, p2 = p1 + a1, p3 = p2 + a2, tot = p3 + a3;
    s[t] = tot;
    __syncthreads();
    #pragma unroll
    for (int off = 1; off < 1024; off <<= 1) {
        int tv = (t >= off) ? s[t - off] : 0;
        __syncthreads();
        s[t] += tv;
        __syncthreads();
    }
    int tex = s[t] - tot;
    if (base     < NBK) boff[base]     = tex;
    if (base + 1 < NBK) boff[base + 1] = tex + p1;
    if (base + 2 < NBK) boff[base + 2] = tex + p2;
    if (base + 3 < NBK) boff[base + 3] = tex + p3;
    if (t == 0) boff[NBK] = E;
}

// ---------- phase 3: placement — LDS counting sort per chunk, atomic window claim,
// ---------- coalesced bucket-major output. rec = (src<<7 | dl<<24, ew) ----------
__global__ __launch_bounds__(512) void k_place(
        const int* __restrict__ src, const int* __restrict__ dst,
        const float* __restrict__ ew, const int* __restrict__ boff,
        int* __restrict__ gcur, int2* __restrict__ recs, int E, int NBK) {
    extern __shared__ char pmem[];
    int2* lrec   = (int2*)pmem;              // PCH records (64 KB)
    int*  addr32 = (int*)(lrec + PCH);       // PCH global addresses (32 KB)
    int*  s      = addr32 + PCH;             // KCAP counts -> exclusive prefix
    int*  cur    = s + KCAP;                 // KCAP chunk-local cursors
    int*  gwin   = cur + KCAP;               // KCAP global window bases
    __shared__ int ts[512];
    int c = blockIdx.x, t = threadIdx.x;
    for (int i = t; i < KCAP; i += 512) { s[i] = 0; cur[i] = 0; }
    __syncthreads();
    int e0 = c * PCH, e1 = min(e0 + PCH, E);
    bool al = ((((size_t)(dst + e0)) | ((size_t)(src + e0)) | ((size_t)(ew + e0))) & 15) == 0;
    int nv = al ? ((e1 - e0) >> 2) : 0;
    const int4*   s4 = (const int4*)(src + e0);
    const int4*   d4 = (const int4*)(dst + e0);
    const float4* w4 = (const float4*)(ew + e0);
    // pass A: count per key
    for (int i = t; i < nv; i += 512) {
        int4 d = d4[i]; int4 sv = s4[i];
        atomicAdd(&s[((d.x >> BSH) << 3) | (sv.x >> RSH)], 1);
        atomicAdd(&s[((d.y >> BSH) << 3) | (sv.y >> RSH)], 1);
        atomicAdd(&s[((d.z >> BSH) << 3) | (sv.z >> RSH)], 1);
        atomicAdd(&s[((d.w >> BSH) << 3) | (sv.w >> RSH)], 1);
    }
    for (int e = e0 + (nv << 2) + t; e < e1; e += 512)
        atomicAdd(&s[((dst[e] >> BSH) << 3) | (src[e] >> RSH)], 1);
    __syncthreads();
    // claim global windows (order within a segment is irrelevant: sums commute)
    for (int k = t; k < NBK; k += 512) {
        int lc = s[k];
        if (lc) gwin[k] = boff[k] + atomicAdd(&gcur[k], lc);
    }
    __syncthreads();
    // in-place exclusive scan of s over KCAP = 512*7 (7 elems/thread + HS over thread sums)
    int base = t * 7;
    int a0=s[base],a1=s[base+1],a2=s[base+2],a3=s[base+3],a4=s[base+4],a5=s[base+5],a6=s[base+6];
    int p1=a0,p2=p1+a1,p3=p2+a2,p4=p3+a3,p5=p4+a4,p6=p5+a5,tot=p6+a6;
    ts[t] = tot;
    __syncthreads();
    #pragma unroll
    for (int off = 1; off < 512; off <<= 1) {
        int tv = (t >= off) ? ts[t - off] : 0;
        __syncthreads();
        ts[t] += tv;
        __syncthreads();
    }
    int tex = ts[t] - tot;
    s[base]=tex; s[base+1]=tex+p1; s[base+2]=tex+p2; s[base+3]=tex+p3;
    s[base+4]=tex+p4; s[base+5]=tex+p5; s[base+6]=tex+p6;
    __syncthreads();
    // pass B: scatter into LDS (record + final global address)
    for (int i = t; i < nv; i += 512) {
        int4 sv = s4[i]; int4 d = d4[i]; float4 wv = w4[i];
        int k, r, sl;
        k=((d.x>>BSH)<<3)|(sv.x>>RSH); r=atomicAdd(&cur[k],1); sl=s[k]+r;
        lrec[sl]=make_int2((sv.x<<7)|((d.x&(BSZ-1))<<24), __float_as_int(wv.x)); addr32[sl]=gwin[k]+r;
        k=((d.y>>BSH)<<3)|(sv.y>>RSH); r=atomicAdd(&cur[k],1); sl=s[k]+r;
        lrec[sl]=make_int2((sv.y<<7)|((d.y&(BSZ-1))<<24), __float_as_int(wv.y)); addr32[sl]=gwin[k]+r;
        k=((d.z>>BSH)<<3)|(sv.z>>RSH); r=atomicAdd(&cur[k],1); sl=s[k]+r;
        lrec[sl]=make_int2((sv.z<<7)|((d.z&(BSZ-1))<<24), __float_as_int(wv.z)); addr32[sl]=gwin[k]+r;
        k=((d.w>>BSH)<<3)|(sv.w>>RSH); r=atomicAdd(&cur[k],1); sl=s[k]+r;
        lrec[sl]=make_int2((sv.w<<7)|((d.w&(BSZ-1))<<24), __float_as_int(wv.w)); addr32[sl]=gwin[k]+r;
    }
    for (int e = e0 + (nv << 2) + t; e < e1; e += 512) {
        int d = dst[e];
        int k = ((d >> BSH) << 3) | (src[e] >> RSH);
        int r = atomicAdd(&cur[k], 1); int sl = s[k] + r;
        lrec[sl] = make_int2((src[e] << 7) | ((d & (BSZ-1)) << 24), __float_as_int(ew[e]));
        addr32[sl] = gwin[k] + r;
    }
    __syncthreads();
    // pass C: linear LDS walk -> coalesced global stores
    int cnt = e1 - e0;
    for (int i = t; i < cnt; i += 512) recs[addr32[i]] = lrec[i];
}

// ---------- weighted in-degree -> dinv ----------
__global__ __launch_bounds__(256) void k_deg(
        const int* __restrict__ boff, const int2* __restrict__ recs,
        float* __restrict__ dinv, int n) {
    __shared__ float ds[BSZ];
    int t = threadIdx.x, b = blockIdx.x;
    ds[t] = 1.0f;                            // self-loop weight
    __syncthreads();
    int s0 = boff[b * NRG], s1 = boff[b * NRG + NRG];
    for (int i = s0 + t; i < s1; i += 256) {
        int2 rc = recs[i];
        atomicAdd(&ds[(unsigned)rc.x >> 24], __int_as_float(rc.y));
    }
    __syncthreads();
    int node = b * BSZ + t;
    if (node < n) dinv[node] = rsqrtf(ds[t]);
}

// ---------- layer 1 GEMM: g1 = fp16(dinv*x@W1), feature-INTERLEAVED rows ----------
// storage slot for feat f: pos = 2*(f&31) + (f>>5) -> a 4B lane-read delivers
// feats (ln, ln+32), making the LDS ds_add in k_agg1 bank-conflict-free.
__global__ void k_gemm1(const float* __restrict__ x, const float* __restrict__ W1,
                        const float* __restrict__ dinv, __half* __restrict__ g1, int n) {
    __shared__ float W1s[FIN * F1];
    __shared__ float xs[64 * FIN];
    int t = threadIdx.x;
    for (int i = t; i < (FIN * F1) / 4; i += 256) ((float4*)W1s)[i] = ((const float4*)W1)[i];
    int row0 = blockIdx.x * 64;
    int nrows = min(64, n - row0);
    const float* xbase = x + (size_t)row0 * FIN;
    int tot = nrows * FIN;
    int totv = tot >> 2;
    for (int i = t; i < totv; i += 256) ((float4*)xs)[i] = ((const float4*)xbase)[i];
    for (int i = (totv << 2) + t; i < tot; i += 256) xs[i] = xbase[i];
    __syncthreads();
    int wave = t >> 6, f = t & 63;
    int pos = ((f & 31) << 1) | (f >> 5);
    for (int rl = wave; rl < nrows; rl += 4) {
        float acc = 0.0f;
        #pragma unroll
        for (int k = 0; k < FIN; k++) acc += xs[rl * FIN + k] * W1s[k * F1 + f];
        int row = row0 + rl;
        g1[(size_t)row * F1 + pos] = __float2half(acc * dinv[row]);
    }
}

// ---------- fused layer-1 aggregate (LDS accumulate, src-range blocked)
// ---------- + self-loop + bias + ReLU + layer-2 GEMM (64->2) ----------
// v2: plain cached int2 loads (NT removed — record stream has 16x line reuse),
//     1024 threads / 16 waves for TLP; proven round-0 load pattern.
__global__ __launch_bounds__(1024, 8) void k_agg1(
        const int* __restrict__ boff, const int2* __restrict__ recs,
        const __half* __restrict__ g1, const float* __restrict__ dinv,
        const float* __restrict__ b1, const float* __restrict__ W2,
        float* __restrict__ g2, int n) {
    extern __shared__ float facc[];          // BSZ*F1 fp32 = 64 KB
    int t = threadIdx.x, b = blockIdx.x;
    for (int i = t; i < (BSZ * F1) >> 2; i += 1024)
        ((float4*)facc)[i] = make_float4(0.f, 0.f, 0.f, 0.f);
    __syncthreads();
    int wv = t >> 6;                         // wave 0..15
    int hl = (t >> 5) & 1;                   // half-wave -> record selector
    int ln = t & 31;                         // lane within half-wave
    const char* g1b = (const char*)g1 + (ln << 2);
    #pragma unroll 1
    for (int rg = 0; rg < NRG; rg++) {       // ranges in order: g1 window L2-resident
        int s0 = boff[b * NRG + rg], s1 = boff[b * NRG + rg + 1];
        for (int base = s0 + wv * 16; base < s1; base += 256) {
            if (base + 16 <= s1) {
                int2 r[8];
                #pragma unroll
                for (int j = 0; j < 8; j++) r[j] = recs[base + 2 * j + hl];
                unsigned hv[8];
                #pragma unroll
                for (int j = 0; j < 8; j++)
                    hv[j] = *(const unsigned*)(g1b + ((unsigned)r[j].x & 0xFFFFFF));
                #pragma unroll
                for (int j = 0; j < 8; j++) {
                    float w = __int_as_float(r[j].y);
                    float2 fv = __half22float2(*(const __half2*)&hv[j]);
                    int fi = ((((unsigned)r[j].x) >> 24) << 6) + ln;
                    atomicAdd(&facc[fi],      w * fv.x);   // feat ln
                    atomicAdd(&facc[fi + 32], w * fv.y);   // feat ln+32
                }
            } else {
                for (int j = 0; j < 8; j++) {
                    int idx = base + 2 * j + hl;
                    if (idx < s1) {
                        int2 rc = recs[idx];
                        unsigned hvv = *(const unsigned*)(g1b + ((unsigned)rc.x & 0xFFFFFF));
                        float w = __int_as_float(rc.y);
                        float2 fv = __half22float2(*(const __half2*)&hvv);
                        int fi = ((((unsigned)rc.x) >> 24) << 6) + ln;
                        atomicAdd(&facc[fi],      w * fv.x);
                        atomicAdd(&facc[fi + 32], w * fv.y);
                    }
                }
            }
        }
    }
    __syncthreads();
    // epilogue: 16 waves x 16 nodes each
    int f = t & 63;
    float bf = b1[f];
    float2 w2v = ((const float2*)W2)[f];
    int pos = ((f & 31) << 1) | (f >> 5);
    for (int dl = wv; dl < BSZ; dl += 16) {
        int node = b * BSZ + dl;
        if (node >= n) break;
        float dv = dinv[node];
        float selfv = __half2float(g1[(size_t)node * F1 + pos]);
        float h = dv * (facc[(dl << 6) + f] + selfv) + bf;   // self-loop w=1
        h = h > 0.0f ? h : 0.0f;
        float z0 = h * w2v.x, z1 = h * w2v.y;
        #pragma unroll
        for (int off = 32; off > 0; off >>= 1) {
            z0 += __shfl_xor(z0, off, 64);
            z1 += __shfl_xor(z1, off, 64);
        }
        if (f == 0) {
            g2[(size_t)node * 2 + 0] = dv * z0;
            g2[(size_t)node * 2 + 1] = dv * z1;
        }
    }
}

// ---------- fused layer-2 aggregate (LDS accumulate) + bias + log_softmax ----------
__global__ __launch_bounds__(256) void k_agg2(
        const int* __restrict__ boff, const int2* __restrict__ recs,
        const float* __restrict__ g2, const float* __restrict__ dinv,
        const float* __restrict__ b2, float* __restrict__ out, int n) {
    __shared__ float a2[BSZ * 2];
    int t = threadIdx.x, b = blockIdx.x;
    a2[t] = 0.0f; a2[t + 256] = 0.0f;
    __syncthreads();
    int s0 = boff[b * NRG], s1 = boff[b * NRG + NRG];
    const char* g2b = (const char*)g2;
    int i = s0 + t;
    for (; i + 768 < s1; i += 1024) {        // 4 gathers in flight
        int2 r0 = recs[i], r1 = recs[i + 256], r2 = recs[i + 512], r3 = recs[i + 768];
        float2 v0 = *(const float2*)(g2b + (((unsigned)r0.x & 0xFFFFFF) >> 4));
        float2 v1 = *(const float2*)(g2b + (((unsigned)r1.x & 0xFFFFFF) >> 4));
        float2 v2 = *(const float2*)(g2b + (((unsigned)r2.x & 0xFFFFFF) >> 4));
        float2 v3 = *(const float2*)(g2b + (((unsigned)r3.x & 0xFFFFFF) >> 4));
        int d0 = (unsigned)r0.x >> 24, d1 = (unsigned)r1.x >> 24;
        int d2 = (unsigned)r2.x >> 24, d3 = (unsigned)r3.x >> 24;
        float w0 = __int_as_float(r0.y), w1 = __int_as_float(r1.y);
        float w2 = __int_as_float(r2.y), w3 = __int_as_float(r3.y);
        atomicAdd(&a2[d0*2], w0*v0.x); atomicAdd(&a2[d0*2+1], w0*v0.y);
        atomicAdd(&a2[d1*2], w1*v1.x); atomicAdd(&a2[d1*2+1], w1*v1.y);
        atomicAdd(&a2[d2*2], w2*v2.x); atomicAdd(&a2[d2*2+1], w2*v2.y);
        atomicAdd(&a2[d3*2], w3*v3.x); atomicAdd(&a2[d3*2+1], w3*v3.y);
    }
    for (; i < s1; i += 256) {
        int2 rc = recs[i];
        float2 gv = *(const float2*)(g2b + (((unsigned)rc.x & 0xFFFFFF) >> 4));
        float w = __int_as_float(rc.y);
        int dl = (unsigned)rc.x >> 24;
        atomicAdd(&a2[dl*2], w*gv.x); atomicAdd(&a2[dl*2+1], w*gv.y);
    }
    __syncthreads();
    int node = b * BSZ + t;
    if (node < n) {
        float dv = dinv[node];
        float2 sv = ((const float2*)g2)[node];     // self-loop
        float z0 = dv * (a2[t*2]     + sv.x) + b2[0];
        float z1 = dv * (a2[t*2 + 1] + sv.y) + b2[1];
        float m = fmaxf(z0, z1);
        float lse = m + logf(expf(z0 - m) + expf(z1 - m));
        ((float2*)out)[node] = make_float2(z0 - lse, z1 - lse);
    }
}

extern "C" void kernel_launch(void* const* d_in, const int* in_sizes, int n_in,
                              void* d_out, int out_size, void* d_ws, size_t ws_size,
                              hipStream_t stream) {
    const float* x  = (const float*)d_in[0];
    const int*   ei = (const int*)d_in[1];    // [2, E]: src row then dst row
    const float* ew = (const float*)d_in[2];
    const float* W1 = (const float*)d_in[3];
    const float* b1 = (const float*)d_in[4];
    const float* W2 = (const float*)d_in[5];
    const float* b2 = (const float*)d_in[6];
    float* out = (float*)d_out;

    int n = in_sizes[0] / FIN;
    int E = in_sizes[2];
    const int* src = ei;
    const int* dst = ei + E;
    int NB  = (n + BSZ - 1) / BSZ;            // 391 for n=100000
    int NBK = NB * NRG;                       // 3128 <= KCAP
    int NCHUNK = (E + PCH - 1) / PCH;         // 391 for E=3.2M

    // workspace carve-out, 16B-aligned
    char* ws = (char*)d_ws;
    size_t off = 0;
    auto alloc = [&](size_t bytes) -> void* {
        void* p = ws + off;
        off += (bytes + 15) & ~(size_t)15;
        return p;
    };
    int*    cnts = (int*)   alloc((size_t)2 * NBK * 4);  // kcnt | gcur
    int*    kcnt = cnts;
    int*    gcur = cnts + NBK;
    int*    boff = (int*)   alloc((size_t)(NBK + 1) * 4);
    float*  dinv = (float*) alloc((size_t)n * 4);
    int2*   recs = (int2*)  alloc((size_t)E * 8);        // 25.6 MB (key-grouped)
    __half* g1   = (__half*)alloc((size_t)n * F1 * 2);   // 12.8 MB
    float*  g2   = (float*) alloc((size_t)n * 2 * 4);

    size_t place_lds = (size_t)PCH * 8 + (size_t)PCH * 4 + 3 * (size_t)KCAP * 4; // 141.3 KB
    size_t agg1_lds  = (size_t)BSZ * F1 * 4;                                     // 64 KB

    hipMemsetAsync(cnts, 0, (size_t)2 * NBK * 4, stream);
    k_hist     <<<NCHUNK, 256, 0, stream>>>(src, dst, kcnt, E, NBK);
    k_scan_buck<<<1, 1024, 0, stream>>>(kcnt, boff, NBK, E);
    k_place    <<<NCHUNK, 512, place_lds, stream>>>(src, dst, ew, boff, gcur, recs, E, NBK);
    k_deg      <<<NB, 256, 0, stream>>>(boff, recs, dinv, n);
    k_gemm1    <<<(n + 63) / 64, 256, 0, stream>>>(x, W1, dinv, g1, n);
    k_agg1     <<<NB, 1024, agg1_lds, stream>>>(boff, recs, g1, dinv, b1, W2, g2, n);
    k_agg2     <<<NB, 256, 0, stream>>>(boff, recs, g2, dinv, b2, out, n);
}